// Round 1
// baseline (2159.068 us; speedup 1.0000x reference)
//
#include <hip/hip_runtime.h>

#define NN 100000

// ---------------- degree ----------------
__global__ void k_deg_init(float* __restrict__ deg, int n) {
    int i = blockIdx.x * blockDim.x + threadIdx.x;
    if (i < n) deg[i] = 1.0f;  // self-loop
}

__global__ void k_deg_count(const int* __restrict__ col, float* __restrict__ deg, int E) {
    int e = blockIdx.x * blockDim.x + threadIdx.x;
    if (e < E) unsafeAtomicAdd(&deg[col[e]], 1.0f);
}

__global__ void k_rsqrt_inplace(float* __restrict__ deg, int n) {
    int i = blockIdx.x * blockDim.x + threadIdx.x;
    if (i < n) deg[i] = rsqrtf(deg[i]);
}

// ---------------- GEMM: Y = (X @ W) * dinv[row], also copy into ACC ----------------
// X: [n,64], W: [64,DOUT]. 256 threads/block, DOUT/4 threads per row.
template<int DOUT>
__global__ __launch_bounds__(256) void k_gemm_scale(
    const float* __restrict__ X, const float* __restrict__ W,
    const float* __restrict__ dinv,
    float* __restrict__ Y, float* __restrict__ ACC, int n)
{
    constexpr int TPR = DOUT / 4;    // threads per row (16 or 8)
    constexpr int R   = 256 / TPR;   // rows per block (16 or 32)
    __shared__ float sW[64 * DOUT];
    __shared__ float sX[R * 64];

    for (int i = threadIdx.x; i < 64 * DOUT; i += 256) sW[i] = W[i];
    int r0 = blockIdx.x * R;
    for (int i = threadIdx.x; i < R * 64; i += 256) {
        int r = r0 + (i >> 6);
        sX[i] = (r < n) ? X[(long long)r * 64 + (i & 63)] : 0.0f;
    }
    __syncthreads();

    int lr  = threadIdx.x / TPR;
    int c4  = (threadIdx.x % TPR) * 4;
    int row = r0 + lr;
    const float* xr = &sX[lr * 64];
    float4 acc = make_float4(0.f, 0.f, 0.f, 0.f);
    #pragma unroll
    for (int k = 0; k < 64; ++k) {
        float xv = xr[k];
        const float* wr = &sW[k * DOUT + c4];
        acc.x = fmaf(xv, wr[0], acc.x);
        acc.y = fmaf(xv, wr[1], acc.y);
        acc.z = fmaf(xv, wr[2], acc.z);
        acc.w = fmaf(xv, wr[3], acc.w);
    }
    if (row < n) {
        float s = dinv[row];
        acc.x *= s; acc.y *= s; acc.z *= s; acc.w *= s;
        *(float4*)&Y[(long long)row * DOUT + c4]   = acc;
        *(float4*)&ACC[(long long)row * DOUT + c4] = acc;  // self-loop init
    }
}

// ---------------- edge scatter: ACC[col] += Y[row] ----------------
template<int DOUT>
__global__ __launch_bounds__(256) void k_scatter(
    const int* __restrict__ rowi, const int* __restrict__ coli,
    const float* __restrict__ Y, float* __restrict__ ACC, int E)
{
    constexpr int TPE = DOUT / 4;  // threads per edge
    long long gid = (long long)blockIdx.x * 256 + threadIdx.x;
    if (gid >= (long long)E * TPE) return;
    int e  = (int)(gid / TPE);
    int c4 = (int)(gid % TPE) * 4;
    int r = rowi[e];
    int c = coli[e];
    float4 v = *(const float4*)&Y[(long long)r * DOUT + c4];
    float* ap = &ACC[(long long)c * DOUT + c4];
    unsafeAtomicAdd(ap + 0, v.x);
    unsafeAtomicAdd(ap + 1, v.y);
    unsafeAtomicAdd(ap + 2, v.z);
    unsafeAtomicAdd(ap + 3, v.w);
}

// ---------------- finalize: O = [relu](dinv*ACC + b) ----------------
template<int DOUT, bool RELU>
__global__ __launch_bounds__(256) void k_finalize(
    const float* __restrict__ ACC, const float* __restrict__ dinv,
    const float* __restrict__ b, float* __restrict__ O, int n)
{
    constexpr int TPR = DOUT / 4;
    long long gid = (long long)blockIdx.x * 256 + threadIdx.x;
    if (gid >= (long long)n * TPR) return;
    int row = (int)(gid / TPR);
    int c4  = (int)(gid % TPR) * 4;
    float s = dinv[row];
    float4 a  = *(const float4*)&ACC[(long long)row * DOUT + c4];
    float4 bb = *(const float4*)&b[c4];
    float4 o;
    o.x = fmaf(s, a.x, bb.x);
    o.y = fmaf(s, a.y, bb.y);
    o.z = fmaf(s, a.z, bb.z);
    o.w = fmaf(s, a.w, bb.w);
    if (RELU) {
        o.x = fmaxf(o.x, 0.f); o.y = fmaxf(o.y, 0.f);
        o.z = fmaxf(o.z, 0.f); o.w = fmaxf(o.w, 0.f);
    }
    *(float4*)&O[(long long)row * DOUT + c4] = o;
}

extern "C" void kernel_launch(void* const* d_in, const int* in_sizes, int n_in,
                              void* d_out, int out_size, void* d_ws, size_t ws_size,
                              hipStream_t stream) {
    const float* x   = (const float*)d_in[0];
    const int*   ei  = (const int*)d_in[1];
    const float* W1  = (const float*)d_in[2];
    const float* b1  = (const float*)d_in[3];
    const float* W2  = (const float*)d_in[4];
    const float* b2  = (const float*)d_in[5];
    float* out = (float*)d_out;

    const int n = NN;
    const int E = in_sizes[1] / 2;
    const int* rowi = ei;       // edge_index[0]
    const int* coli = ei + E;   // edge_index[1]

    // workspace layout (floats)
    float* ws   = (float*)d_ws;
    float* dinv = ws;                       // n
    float* Y1   = dinv + 100352;            // n*64
    float* ACC1 = Y1 + (size_t)n * 64;      // n*64 (becomes H after finalize)
    float* Y2   = ACC1 + (size_t)n * 64;    // n*32
    float* ACC2 = Y2 + (size_t)n * 32;      // n*32

    // degree (shared across both layers)
    k_deg_init<<<(n + 255) / 256, 256, 0, stream>>>(dinv, n);
    k_deg_count<<<(E + 255) / 256, 256, 0, stream>>>(coli, dinv, E);
    k_rsqrt_inplace<<<(n + 255) / 256, 256, 0, stream>>>(dinv, n);

    // ---- layer 1 ----
    {
        constexpr int D = 64;
        int gemm_blocks = (n + 15) / 16;
        k_gemm_scale<D><<<gemm_blocks, 256, 0, stream>>>(x, W1, dinv, Y1, ACC1, n);
        long long tot = (long long)E * (D / 4);
        k_scatter<D><<<(int)((tot + 255) / 256), 256, 0, stream>>>(rowi, coli, Y1, ACC1, E);
        long long ft = (long long)n * (D / 4);
        k_finalize<D, true><<<(int)((ft + 255) / 256), 256, 0, stream>>>(ACC1, dinv, b1, ACC1, n);
    }
    // ---- layer 2 ----
    {
        constexpr int D = 32;
        int gemm_blocks = (n + 31) / 32;
        k_gemm_scale<D><<<gemm_blocks, 256, 0, stream>>>(ACC1, W2, dinv, Y2, ACC2, n);
        long long tot = (long long)E * (D / 4);
        k_scatter<D><<<(int)((tot + 255) / 256), 256, 0, stream>>>(rowi, coli, Y2, ACC2, E);
        long long ft = (long long)n * (D / 4);
        k_finalize<D, false><<<(int)((ft + 255) / 256), 256, 0, stream>>>(ACC2, dinv, b2, ACC2, n);
    }
    // copy final result to d_out (finalize wrote ACC2; write directly instead)
    // -- actually write finalize straight to out: redo with out pointer
    // (kept simple: run finalize again into out is wasteful; instead we point it at out)
    // NOTE: the call above wrote ACC2; to avoid an extra pass we simply also
    // launch a copy kernel. Cheaper: just write finalize directly to out.
    hipMemcpyAsync(out, ACC2, (size_t)n * 32 * sizeof(float), hipMemcpyDeviceToDevice, stream);
}

// Round 2
// 560.171 us; speedup vs baseline: 3.8543x; 3.8543x over previous
//
#include <hip/hip_runtime.h>

#define NN 100000

// ================= CSR build =================
__global__ void k_count(const int* __restrict__ coli, int* __restrict__ cnt, int E) {
    int e = blockIdx.x * blockDim.x + threadIdx.x;
    if (e < E) atomicAdd(&cnt[coli[e]], 1);
}

// single-block exclusive scan over cnt -> off (and cursor copy), plus dinv = rsqrt(cnt+1)
__global__ __launch_bounds__(1024) void k_scan(
    const int* __restrict__ cnt, int* __restrict__ off, int* __restrict__ cursor,
    float* __restrict__ dinv, int n)
{
    __shared__ int sh[1024];
    __shared__ int carry_s;
    if (threadIdx.x == 0) carry_s = 0;
    __syncthreads();
    for (int base = 0; base < n; base += 1024) {
        int i = base + threadIdx.x;
        int v = (i < n) ? cnt[i] : 0;
        sh[threadIdx.x] = v;
        __syncthreads();
        #pragma unroll
        for (int d = 1; d < 1024; d <<= 1) {
            int t = (threadIdx.x >= d) ? sh[threadIdx.x - d] : 0;
            __syncthreads();
            sh[threadIdx.x] += t;
            __syncthreads();
        }
        int incl  = sh[threadIdx.x];
        int carry = carry_s;
        if (i < n) {
            int excl = carry + incl - v;
            off[i] = excl;
            cursor[i] = excl;
            dinv[i] = rsqrtf((float)(v + 1));   // +1 self-loop
        }
        __syncthreads();
        if (threadIdx.x == 1023) carry_s = carry + sh[1023];
        __syncthreads();
    }
    if (threadIdx.x == 0) off[n] = carry_s;
}

__global__ void k_fill(const int* __restrict__ rowi, const int* __restrict__ coli,
                       int* __restrict__ cursor, int* __restrict__ srcs, int E) {
    int e = blockIdx.x * blockDim.x + threadIdx.x;
    if (e < E) {
        int p = atomicAdd(&cursor[coli[e]], 1);
        srcs[p] = rowi[e];
    }
}

// ================= GEMM: Y = (X @ W) * dinv[row] =================
// X: [n,64], W: [64,DOUT]. 256 threads/block, DOUT/4 threads per row.
template<int DOUT>
__global__ __launch_bounds__(256) void k_gemm_scale(
    const float* __restrict__ X, const float* __restrict__ W,
    const float* __restrict__ dinv, float* __restrict__ Y, int n)
{
    constexpr int TPR = DOUT / 4;
    constexpr int R   = 256 / TPR;
    __shared__ float sW[64 * DOUT];
    __shared__ float sX[R * 64];

    for (int i = threadIdx.x; i < 64 * DOUT; i += 256) sW[i] = W[i];
    int r0 = blockIdx.x * R;
    for (int i = threadIdx.x; i < R * 64; i += 256) {
        int r = r0 + (i >> 6);
        sX[i] = (r < n) ? X[(size_t)r * 64 + (i & 63)] : 0.0f;
    }
    __syncthreads();

    int lr  = threadIdx.x / TPR;
    int c4  = (threadIdx.x % TPR) * 4;
    int row = r0 + lr;
    const float* xr = &sX[lr * 64];
    float4 acc = make_float4(0.f, 0.f, 0.f, 0.f);
    #pragma unroll
    for (int k = 0; k < 64; ++k) {
        float xv = xr[k];
        const float* wr = &sW[k * DOUT + c4];
        acc.x = fmaf(xv, wr[0], acc.x);
        acc.y = fmaf(xv, wr[1], acc.y);
        acc.z = fmaf(xv, wr[2], acc.z);
        acc.w = fmaf(xv, wr[3], acc.w);
    }
    if (row < n) {
        float s = dinv[row];
        acc.x *= s; acc.y *= s; acc.z *= s; acc.w *= s;
        *(float4*)&Y[(size_t)row * DOUT + c4] = acc;
    }
}

// ================= CSR aggregate: O = [relu](dinv[i]*(Y[i] + sum_in Y[src]) + b) ===========
// D=64: one 64-lane wave per node. 256 thr/block -> 4 nodes/block.
template<bool RELU>
__global__ __launch_bounds__(256) void k_agg64(
    const float* __restrict__ Y, const int* __restrict__ off, const int* __restrict__ srcs,
    const float* __restrict__ dinv, const float* __restrict__ bias,
    float* __restrict__ O, int n)
{
    int node = blockIdx.x * 4 + (threadIdx.x >> 6);
    if (node >= n) return;
    int c = threadIdx.x & 63;
    int j = off[node], end = off[node + 1];
    float s0 = Y[(size_t)node * 64 + c];   // self-loop
    float s1 = 0.f, s2 = 0.f, s3 = 0.f;
    for (; j + 4 <= end; j += 4) {
        int a = srcs[j], b = srcs[j + 1], c2 = srcs[j + 2], d = srcs[j + 3];
        s0 += Y[(size_t)a  * 64 + c];
        s1 += Y[(size_t)b  * 64 + c];
        s2 += Y[(size_t)c2 * 64 + c];
        s3 += Y[(size_t)d  * 64 + c];
    }
    for (; j < end; ++j) s0 += Y[(size_t)srcs[j] * 64 + c];
    float s = (s0 + s1) + (s2 + s3);
    float o = fmaf(dinv[node], s, bias[c]);
    if (RELU) o = fmaxf(o, 0.f);
    O[(size_t)node * 64 + c] = o;
}

// D=32: one 32-lane half-wave per node. 256 thr/block -> 8 nodes/block.
template<bool RELU>
__global__ __launch_bounds__(256) void k_agg32(
    const float* __restrict__ Y, const int* __restrict__ off, const int* __restrict__ srcs,
    const float* __restrict__ dinv, const float* __restrict__ bias,
    float* __restrict__ O, int n)
{
    int node = blockIdx.x * 8 + (threadIdx.x >> 5);
    if (node >= n) return;
    int c = threadIdx.x & 31;
    int j = off[node], end = off[node + 1];
    float s0 = Y[(size_t)node * 32 + c];   // self-loop
    float s1 = 0.f, s2 = 0.f, s3 = 0.f;
    for (; j + 4 <= end; j += 4) {
        int a = srcs[j], b = srcs[j + 1], c2 = srcs[j + 2], d = srcs[j + 3];
        s0 += Y[(size_t)a  * 32 + c];
        s1 += Y[(size_t)b  * 32 + c];
        s2 += Y[(size_t)c2 * 32 + c];
        s3 += Y[(size_t)d  * 32 + c];
    }
    for (; j < end; ++j) s0 += Y[(size_t)srcs[j] * 32 + c];
    float s = (s0 + s1) + (s2 + s3);
    float o = fmaf(dinv[node], s, bias[c]);
    if (RELU) o = fmaxf(o, 0.f);
    O[(size_t)node * 32 + c] = o;
}

extern "C" void kernel_launch(void* const* d_in, const int* in_sizes, int n_in,
                              void* d_out, int out_size, void* d_ws, size_t ws_size,
                              hipStream_t stream) {
    const float* x  = (const float*)d_in[0];
    const int*   ei = (const int*)d_in[1];
    const float* W1 = (const float*)d_in[2];
    const float* b1 = (const float*)d_in[3];
    const float* W2 = (const float*)d_in[4];
    const float* b2 = (const float*)d_in[5];
    float* out = (float*)d_out;

    const int n = NN;
    const int E = in_sizes[1] / 2;
    const int* rowi = ei;
    const int* coli = ei + E;

    // workspace layout
    char* p = (char*)d_ws;
    int*   cnt    = (int*)p;            p += (size_t)n * 4;
    int*   off    = (int*)p;            p += (size_t)(n + 1) * 4;
    int*   cursor = (int*)p;            p += (size_t)n * 4;
    float* dinv   = (float*)p;          p += (size_t)n * 4;
    int*   srcs   = (int*)p;            p += (size_t)E * 4;
    float* Y1     = (float*)p;          p += (size_t)n * 64 * 4;
    float* H      = (float*)p;          p += (size_t)n * 64 * 4;
    float* Y2     = (float*)p;          p += (size_t)n * 32 * 4;

    // ---- CSR build (shared across both layers) ----
    hipMemsetAsync(cnt, 0, (size_t)n * 4, stream);
    k_count<<<(E + 255) / 256, 256, 0, stream>>>(coli, cnt, E);
    k_scan<<<1, 1024, 0, stream>>>(cnt, off, cursor, dinv, n);
    k_fill<<<(E + 255) / 256, 256, 0, stream>>>(rowi, coli, cursor, srcs, E);

    // ---- layer 1 (in 64 -> hid 64, relu) ----
    k_gemm_scale<64><<<(n + 15) / 16, 256, 0, stream>>>(x, W1, dinv, Y1, n);
    k_agg64<true><<<(n + 3) / 4, 256, 0, stream>>>(Y1, off, srcs, dinv, b1, H, n);

    // ---- layer 2 (hid 64 -> out 32) ----
    k_gemm_scale<32><<<(n + 31) / 32, 256, 0, stream>>>(H, W2, dinv, Y2, n);
    k_agg32<false><<<(n + 7) / 8, 256, 0, stream>>>(Y2, off, srcs, dinv, b2, out, n);
}

// Round 3
// 386.931 us; speedup vs baseline: 5.5800x; 1.4477x over previous
//
#include <hip/hip_runtime.h>

#define NN 100000

// ================= CSR build =================
__global__ void k_count(const int* __restrict__ coli, int* __restrict__ cnt, int E) {
    int e = blockIdx.x * blockDim.x + threadIdx.x;
    if (e < E) atomicAdd(&cnt[coli[e]], 1);
}

// ---- hierarchical scan: pass 1 (per-1024-block local exclusive scan + block sums + dinv) ----
__global__ __launch_bounds__(1024) void k_scan1(
    const int* __restrict__ cnt, int* __restrict__ off, float* __restrict__ dinv,
    int* __restrict__ blksum, int n)
{
    __shared__ int sh[1024];
    int i = blockIdx.x * 1024 + threadIdx.x;
    int v = (i < n) ? cnt[i] : 0;
    sh[threadIdx.x] = v;
    __syncthreads();
    #pragma unroll
    for (int d = 1; d < 1024; d <<= 1) {
        int t = (threadIdx.x >= d) ? sh[threadIdx.x - d] : 0;
        __syncthreads();
        sh[threadIdx.x] += t;
        __syncthreads();
    }
    if (i < n) {
        off[i]  = sh[threadIdx.x] - v;   // local exclusive
        dinv[i] = rsqrtf((float)(v + 1)); // +1 self-loop
    }
    if (threadIdx.x == 1023) blksum[blockIdx.x] = sh[1023];
}

// ---- pass 2: exclusive scan of block sums (nb <= 128), single block ----
__global__ __launch_bounds__(128) void k_scan2(int* __restrict__ blksum, int nb) {
    __shared__ int sh[128];
    int v = (threadIdx.x < nb) ? blksum[threadIdx.x] : 0;
    sh[threadIdx.x] = v;
    __syncthreads();
    #pragma unroll
    for (int d = 1; d < 128; d <<= 1) {
        int t = (threadIdx.x >= d) ? sh[threadIdx.x - d] : 0;
        __syncthreads();
        sh[threadIdx.x] += t;
        __syncthreads();
    }
    if (threadIdx.x < nb) blksum[threadIdx.x] = sh[threadIdx.x] - v;  // exclusive
}

// ---- pass 3: add block offsets, produce final off + cursor; write off[n]=E ----
__global__ __launch_bounds__(256) void k_scan3(
    int* __restrict__ off, int* __restrict__ cursor,
    const int* __restrict__ blksum, int n, int E)
{
    int i = blockIdx.x * 256 + threadIdx.x;
    if (i < n) {
        int o = off[i] + blksum[i >> 10];
        off[i] = o;
        cursor[i] = o;
    }
    if (i == 0) off[n] = E;
}

__global__ void k_fill(const int* __restrict__ rowi, const int* __restrict__ coli,
                       int* __restrict__ cursor, int* __restrict__ srcs, int E) {
    int e = blockIdx.x * blockDim.x + threadIdx.x;
    if (e < E) {
        int p = atomicAdd(&cursor[coli[e]], 1);
        srcs[p] = rowi[e];
    }
}

// ================= GEMM: Y = (X @ W) * dinv[row] =================
template<int DOUT>
__global__ __launch_bounds__(256) void k_gemm_scale(
    const float* __restrict__ X, const float* __restrict__ W,
    const float* __restrict__ dinv, float* __restrict__ Y, int n)
{
    constexpr int TPR = DOUT / 4;
    constexpr int R   = 256 / TPR;
    __shared__ float sW[64 * DOUT];
    __shared__ float sX[R * 64];

    for (int i = threadIdx.x; i < 64 * DOUT; i += 256) sW[i] = W[i];
    int r0 = blockIdx.x * R;
    for (int i = threadIdx.x; i < R * 64; i += 256) {
        int r = r0 + (i >> 6);
        sX[i] = (r < n) ? X[(size_t)r * 64 + (i & 63)] : 0.0f;
    }
    __syncthreads();

    int lr  = threadIdx.x / TPR;
    int c4  = (threadIdx.x % TPR) * 4;
    int row = r0 + lr;
    const float* xr = &sX[lr * 64];
    float4 acc = make_float4(0.f, 0.f, 0.f, 0.f);
    #pragma unroll
    for (int k = 0; k < 64; ++k) {
        float xv = xr[k];
        const float* wr = &sW[k * DOUT + c4];
        acc.x = fmaf(xv, wr[0], acc.x);
        acc.y = fmaf(xv, wr[1], acc.y);
        acc.z = fmaf(xv, wr[2], acc.z);
        acc.w = fmaf(xv, wr[3], acc.w);
    }
    if (row < n) {
        float s = dinv[row];
        acc.x *= s; acc.y *= s; acc.z *= s; acc.w *= s;
        *(float4*)&Y[(size_t)row * DOUT + c4] = acc;
    }
}

// ================= CSR aggregate: O = [relu](dinv[i]*(Y[i] + sum_in Y[src]) + b) ===========
template<bool RELU>
__global__ __launch_bounds__(256) void k_agg64(
    const float* __restrict__ Y, const int* __restrict__ off, const int* __restrict__ srcs,
    const float* __restrict__ dinv, const float* __restrict__ bias,
    float* __restrict__ O, int n)
{
    int node = blockIdx.x * 4 + (threadIdx.x >> 6);
    if (node >= n) return;
    int c = threadIdx.x & 63;
    int j = off[node], end = off[node + 1];
    float s0 = Y[(size_t)node * 64 + c];   // self-loop
    float s1 = 0.f, s2 = 0.f, s3 = 0.f;
    for (; j + 4 <= end; j += 4) {
        int a = srcs[j], b = srcs[j + 1], c2 = srcs[j + 2], d = srcs[j + 3];
        s0 += Y[(size_t)a  * 64 + c];
        s1 += Y[(size_t)b  * 64 + c];
        s2 += Y[(size_t)c2 * 64 + c];
        s3 += Y[(size_t)d  * 64 + c];
    }
    for (; j < end; ++j) s0 += Y[(size_t)srcs[j] * 64 + c];
    float s = (s0 + s1) + (s2 + s3);
    float o = fmaf(dinv[node], s, bias[c]);
    if (RELU) o = fmaxf(o, 0.f);
    O[(size_t)node * 64 + c] = o;
}

template<bool RELU>
__global__ __launch_bounds__(256) void k_agg32(
    const float* __restrict__ Y, const int* __restrict__ off, const int* __restrict__ srcs,
    const float* __restrict__ dinv, const float* __restrict__ bias,
    float* __restrict__ O, int n)
{
    int node = blockIdx.x * 8 + (threadIdx.x >> 5);
    if (node >= n) return;
    int c = threadIdx.x & 31;
    int j = off[node], end = off[node + 1];
    float s0 = Y[(size_t)node * 32 + c];   // self-loop
    float s1 = 0.f, s2 = 0.f, s3 = 0.f;
    for (; j + 4 <= end; j += 4) {
        int a = srcs[j], b = srcs[j + 1], c2 = srcs[j + 2], d = srcs[j + 3];
        s0 += Y[(size_t)a  * 32 + c];
        s1 += Y[(size_t)b  * 32 + c];
        s2 += Y[(size_t)c2 * 32 + c];
        s3 += Y[(size_t)d  * 32 + c];
    }
    for (; j < end; ++j) s0 += Y[(size_t)srcs[j] * 32 + c];
    float s = (s0 + s1) + (s2 + s3);
    float o = fmaf(dinv[node], s, bias[c]);
    if (RELU) o = fmaxf(o, 0.f);
    O[(size_t)node * 32 + c] = o;
}

extern "C" void kernel_launch(void* const* d_in, const int* in_sizes, int n_in,
                              void* d_out, int out_size, void* d_ws, size_t ws_size,
                              hipStream_t stream) {
    const float* x  = (const float*)d_in[0];
    const int*   ei = (const int*)d_in[1];
    const float* W1 = (const float*)d_in[2];
    const float* b1 = (const float*)d_in[3];
    const float* W2 = (const float*)d_in[4];
    const float* b2 = (const float*)d_in[5];
    float* out = (float*)d_out;

    const int n = NN;
    const int E = in_sizes[1] / 2;
    const int* rowi = ei;
    const int* coli = ei + E;

    // workspace layout
    char* p = (char*)d_ws;
    int*   cnt    = (int*)p;            p += (size_t)n * 4;
    int*   off    = (int*)p;            p += (size_t)(n + 1) * 4;
    int*   cursor = (int*)p;            p += (size_t)n * 4;
    float* dinv   = (float*)p;          p += (size_t)n * 4;
    int*   blksum = (int*)p;            p += (size_t)128 * 4;
    int*   srcs   = (int*)p;            p += (size_t)E * 4;
    float* Y1     = (float*)p;          p += (size_t)n * 64 * 4;
    float* H      = (float*)p;          p += (size_t)n * 64 * 4;
    float* Y2     = (float*)p;          p += (size_t)n * 32 * 4;

    // ---- CSR build (shared across both layers) ----
    hipMemsetAsync(cnt, 0, (size_t)n * 4, stream);
    k_count<<<(E + 255) / 256, 256, 0, stream>>>(coli, cnt, E);
    int nb = (n + 1023) / 1024;  // 98
    k_scan1<<<nb, 1024, 0, stream>>>(cnt, off, dinv, blksum, n);
    k_scan2<<<1, 128, 0, stream>>>(blksum, nb);
    k_scan3<<<(n + 255) / 256, 256, 0, stream>>>(off, cursor, blksum, n, E);
    k_fill<<<(E + 255) / 256, 256, 0, stream>>>(rowi, coli, cursor, srcs, E);

    // ---- layer 1 (in 64 -> hid 64, relu) ----
    k_gemm_scale<64><<<(n + 15) / 16, 256, 0, stream>>>(x, W1, dinv, Y1, n);
    k_agg64<true><<<(n + 3) / 4, 256, 0, stream>>>(Y1, off, srcs, dinv, b1, H, n);

    // ---- layer 2 (hid 64 -> out 32) ----
    k_gemm_scale<32><<<(n + 31) / 32, 256, 0, stream>>>(H, W2, dinv, Y2, n);
    k_agg32<false><<<(n + 7) / 8, 256, 0, stream>>>(Y2, off, srcs, dinv, b2, out, n);
}